// Round 7
// baseline (1232.861 us; speedup 1.0000x reference)
//
#include <hip/hip_runtime.h>
#include <hip/hip_bf16.h>

// ClusterMemory forward: loss = mean_i [ logsumexp_j( <x_i, f_j>/T ) - <x_i, f_{t_i}>/T ]
// x_i = inputs_i / max(||inputs_i||, 1e-12),  T = 0.05,  B=4096, N=131072, D=256.
//
// R7: revert R6 (spill + 1-block/CU). R4 geometry (BN=128, m-rep=2, 84 VGPR)
// with ring-3 LDS (48KB -> 3 blocks/CU, 24 waves) for anti-phased barrier
// coverage. STAGE placed AFTER the barrier (makes ring-3 + stage-ahead-2 safe).
// Counted vmcnt(2); vmcnt(0) only in the final phase. Max-free LSE epilogue
// (native v_exp_f32), A in registers for full K=256, B via global_load_lds(16B)
// inverse-swizzled, setprio around MFMA, bijective XCD swizzle.

typedef __attribute__((ext_vector_type(8))) short bf16x8;
typedef __attribute__((ext_vector_type(4))) float f32x4;
typedef __attribute__((address_space(1))) unsigned int u32g;
typedef __attribute__((address_space(3))) unsigned int u32l;

#define B_ROWS   4096
#define N_FEATS  131072
#define D_DIM    256
// (1/0.05) * log2(e)
#define SCALE_B2 28.853900817779268f
#define LN2F     0.69314718055994531f

#define BM 128
#define BN 128
#define BKT 64
#define NCHUNK 32                       // grid y
#define COLS_PB (N_FEATS / NCHUNK)      // 4096 cols per block
#define NTILES  (COLS_PB / BN)          // 32 column tiles per block
#define TILE_B  (BN * BKT * 2)          // 16384 bytes per B tile
#define NSLICE  (NCHUNK * 2)            // 64 partial slices per row

#define E2(x) __builtin_amdgcn_exp2f(x)

static __device__ __forceinline__ unsigned short f2bf(float x) {
    __hip_bfloat16 h = __float2bfloat16(x);
    return __builtin_bit_cast(unsigned short, h);
}
static __device__ __forceinline__ float bf2f(unsigned short u) {
    return __builtin_bit_cast(float, ((unsigned int)u) << 16);
}

// ---------------- kernel 1: row-normalize + scale + cvt to bf16 ----------------
__global__ __launch_bounds__(64) void k_normalize(const float* __restrict__ in,
                                                  unsigned short* __restrict__ xb) {
    const int row  = blockIdx.x;
    const int lane = threadIdx.x;
    float4 v = *(const float4*)(in + (size_t)row * D_DIM + lane * 4);
    float ss = v.x * v.x + v.y * v.y + v.z * v.z + v.w * v.w;
#pragma unroll
    for (int mask = 1; mask < 64; mask <<= 1) ss += __shfl_xor(ss, mask);
    const float sc = SCALE_B2 / fmaxf(sqrtf(ss), 1e-12f);
    ushort4 o;
    o.x = f2bf(v.x * sc); o.y = f2bf(v.y * sc);
    o.z = f2bf(v.z * sc); o.w = f2bf(v.w * sc);
    *(ushort4*)(xb + (size_t)row * D_DIM + lane * 4) = o;
}

// ---------------- kernel 2: features fp32 -> bf16 ----------------
__global__ __launch_bounds__(256) void k_cvt_feats(const float* __restrict__ f,
                                                   unsigned short* __restrict__ fb) {
    const int total4 = N_FEATS * D_DIM / 4;
    const int stride = gridDim.x * blockDim.x;
    for (int i = blockIdx.x * blockDim.x + threadIdx.x; i < total4; i += stride) {
        float4 v = ((const float4*)f)[i];
        ushort4 o;
        o.x = f2bf(v.x); o.y = f2bf(v.y); o.z = f2bf(v.z); o.w = f2bf(v.w);
        ((ushort4*)fb)[i] = o;
    }
}

// ---- staging: issue 2 global_load_lds (16B) for tile t_ into buffer at byte off ----
#define STAGE(t_, bOff_) do {                                                         \
        const int nt_ = (t_) >> 2, kt_ = (t_) & 3;                                    \
        const unsigned short* s_ = fb + (nbase + (size_t)nt_ * BN) * D_DIM + kt_ * BKT; \
        char* d_ = &Bs[(bOff_) + dBase];                                              \
        __builtin_amdgcn_global_load_lds((const u32g*)(s_ + e0), (u32l*)d_, 16, 0, 0);\
        __builtin_amdgcn_global_load_lds((const u32g*)(s_ + e1), (u32l*)(d_ + 8192), 16, 0, 0); \
    } while (0)

// ---- compute: 8 swizzled ds_read_b128 + 16 MFMA; ktL literal, bOff_ runtime ----
#define COMPUTE(ktL, bOff_) do {                                                      \
        const char* buf_ = &Bs[(bOff_)];                                              \
        bf16x8 bfr[2][4];                                                             \
        _Pragma("unroll")                                                             \
        for (int ks2 = 0; ks2 < 2; ++ks2)                                             \
        _Pragma("unroll")                                                             \
            for (int n = 0; n < 4; ++n) {                                             \
                const int col = wc * 64 + n * 16 + l15;                               \
                const int off = (col * 128 + ks2 * 64 + l4 * 16) ^ ((col & 7) << 4);  \
                bfr[ks2][n] = *(const bf16x8*)(buf_ + off);                           \
            }                                                                         \
        __builtin_amdgcn_s_setprio(1);                                                \
        _Pragma("unroll")                                                             \
        for (int ks2 = 0; ks2 < 2; ++ks2)                                             \
        _Pragma("unroll")                                                             \
            for (int m = 0; m < 2; ++m)                                               \
        _Pragma("unroll")                                                             \
                for (int n = 0; n < 4; ++n)                                           \
                    acc[m][n] = __builtin_amdgcn_mfma_f32_16x16x32_bf16(              \
                        afr[m][(ktL) * 2 + ks2], bfr[ks2][n], acc[m][n], 0, 0, 0);    \
        __builtin_amdgcn_s_setprio(0);                                                \
    } while (0)

// vmcnt(N)+barrier
#define VMB(n_) asm volatile("s_waitcnt vmcnt(" #n_ ")\ns_barrier" ::: "memory")
// rotate a ring-3 byte offset
#define ROT3(x_) x_ = ((x_) == 2 * TILE_B) ? 0 : (x_) + TILE_B

// ---- per-column-tile exp2-accumulate (max-free; logits bounded); resets acc ----
#define EPI() do {                                                                    \
        _Pragma("unroll")                                                             \
        for (int m = 0; m < 2; ++m)                                                   \
        _Pragma("unroll")                                                             \
            for (int j = 0; j < 4; ++j) {                                             \
                const int r = m * 4 + j;                                              \
                s_run[r] += (E2(acc[m][0][j]) + E2(acc[m][1][j]))                     \
                          + (E2(acc[m][2][j]) + E2(acc[m][3][j]));                    \
            }                                                                         \
        _Pragma("unroll")                                                             \
        for (int m = 0; m < 2; ++m)                                                   \
        _Pragma("unroll")                                                             \
            for (int n = 0; n < 4; ++n) acc[m][n] = (f32x4){0.f, 0.f, 0.f, 0.f};      \
    } while (0)

// ---- fp32-fallback staging (reg-cvt, write-side swizzle) ----
#define LOADCVT(t_) do {                                                              \
        const int nt_ = (t_) >> 2, kt_ = (t_) & 3;                                    \
        const float* s0_ = featf + (nbase + (size_t)nt_ * BN + fc0) * D_DIM + kt_ * BKT + fk0; \
        const float* s1_ = featf + (nbase + (size_t)nt_ * BN + fc1) * D_DIM + kt_ * BKT + fk1; \
        float4 a0 = *(const float4*)s0_, a1 = *(const float4*)(s0_ + 4);              \
        float4 b0 = *(const float4*)s1_, b1 = *(const float4*)(s1_ + 4);              \
        unsigned short ua[8] = {f2bf(a0.x), f2bf(a0.y), f2bf(a0.z), f2bf(a0.w),       \
                                f2bf(a1.x), f2bf(a1.y), f2bf(a1.z), f2bf(a1.w)};      \
        unsigned short ub[8] = {f2bf(b0.x), f2bf(b0.y), f2bf(b0.z), f2bf(b0.w),       \
                                f2bf(b1.x), f2bf(b1.y), f2bf(b1.z), f2bf(b1.w)};      \
        ra = *(int4*)ua; rb = *(int4*)ub;                                             \
    } while (0)
#define WRITEB(bOff_) do {                                                            \
        char* d_ = &Bs[(bOff_)];                                                      \
        *(int4*)(d_ + wo0) = ra;                                                      \
        *(int4*)(d_ + wo1) = rb;                                                      \
    } while (0)

// ---------------- kernel 3: fused GEMM + max-free base-2 LSE ----------------
// grid = (32 m-blocks, 32 n-chunks), block = 512 (8 waves: 4 wr x 2 wc, 32Mx64N each)
// ring-3 LDS (48KB) -> 3 blocks/CU
template <bool BF16B>
__global__ __launch_bounds__(512, 6) void k_lse_gemm(
    const unsigned short* __restrict__ xb,
    const float* __restrict__ featf,
    const unsigned short* __restrict__ fb,
    float* __restrict__ partials)
{
    __shared__ char Bs[3 * TILE_B];   // 48 KB ring

    // bijective XCD swizzle (1024 blocks % 8 == 0)
    const int hw  = blockIdx.y * 32 + blockIdx.x;
    const int lid = (hw & 7) * 128 + (hw >> 3);
    const int bx  = lid & 31;         // m-block
    const int by  = lid >> 5;         // n-chunk

    const int tid  = threadIdx.x;
    const int lane = tid & 63;
    const int w    = tid >> 6;
    const int wr   = w >> 1;          // 0..3 : 32-row slice
    const int wc   = w & 1;           // 0..1 : 64-col slice
    const int l15  = lane & 15;
    const int l4   = lane >> 4;

    const int brow     = bx * BM;
    const size_t nbase = (size_t)by * COLS_PB;

    // ---- A fragments in registers for full K=256 (loaded once, L2-resident) ----
    bf16x8 afr[2][8];
#pragma unroll
    for (int m = 0; m < 2; ++m) {
        const unsigned short* ap =
            xb + (size_t)(brow + wr * 32 + m * 16 + l15) * D_DIM + l4 * 8;
#pragma unroll
        for (int ks = 0; ks < 8; ++ks)
            afr[m][ks] = *(const bf16x8*)(ap + ks * 32);
    }

    f32x4 acc[2][4];
#pragma unroll
    for (int m = 0; m < 2; ++m)
#pragma unroll
        for (int n = 0; n < 4; ++n) acc[m][n] = (f32x4){0.f, 0.f, 0.f, 0.f};
    float s_run[8];
#pragma unroll
    for (int r = 0; r < 8; ++r) s_run[r] = 0.f;

    if (BF16B) {
        // inverse-swizzled source element offsets (constant across tiles)
        int e0, e1;
        {
            const int p0 = w * 1024 + lane * 16;
            const int c0 = p0 >> 7;
            e0 = c0 * D_DIM + ((((p0 ^ ((c0 & 7) << 4)) >> 4) & 7) * 8);
            const int p1 = p0 + 8192;
            const int c1 = p1 >> 7;
            e1 = c1 * D_DIM + ((((p1 ^ ((c1 & 7) << 4)) >> 4) & 7) * 8);
        }
        const int dBase = w * 1024;   // wave-uniform LDS slice

        int rRo = 0;              // read-buffer byte offset: tile t -> (t%3)*TILE_B
        int rSo = 2 * TILE_B;     // stage-target: tile t+2 -> ((t+2)%3)*TILE_B

        STAGE(0, 0);
        STAGE(1, TILE_B);
        // main loop: nt = 0..30 (phases t = nt*4+kt, staging t+2 <= 125)
        for (int nt = 0; nt < NTILES - 1; ++nt) {
            const int t0 = nt * 4;
            // kt = 0
            VMB(2); STAGE(t0 + 2, rSo); COMPUTE(0, rRo); ROT3(rRo); ROT3(rSo);
            // kt = 1
            VMB(2); STAGE(t0 + 3, rSo); COMPUTE(1, rRo); ROT3(rRo); ROT3(rSo);
            // kt = 2
            VMB(2); STAGE(t0 + 4, rSo); COMPUTE(2, rRo); ROT3(rRo); ROT3(rSo);
            // kt = 3
            VMB(2); STAGE(t0 + 5, rSo); COMPUTE(3, rRo); ROT3(rRo); ROT3(rSo);
            EPI();
        }
        // peeled nt = 31: phases 124..127; tiles 126,127 staged at 124,125
        VMB(2); STAGE(126, rSo); COMPUTE(0, rRo); ROT3(rRo); ROT3(rSo);
        VMB(2); STAGE(127, rSo); COMPUTE(1, rRo); ROT3(rRo);
        VMB(2); COMPUTE(2, rRo); ROT3(rRo);
        VMB(0); COMPUTE(3, rRo);
        EPI();
    } else {
        // fp32 fallback: reg-staged cvt, 2-buffer, __syncthreads discipline
        const int c0 = tid, c1 = tid + 512;
        const int fc0 = c0 >> 3, fk0 = (c0 & 7) * 8;
        const int fc1 = c1 >> 3, fk1 = (c1 & 7) * 8;
        const int wo0 = (fc0 * 128 + fk0 * 2) ^ ((fc0 & 7) << 4);
        const int wo1 = (fc1 * 128 + fk1 * 2) ^ ((fc1 & 7) << 4);
        int4 ra, rb;
        LOADCVT(0); WRITEB(0);
        __syncthreads();
        for (int nt = 0; nt < NTILES; ++nt) {
            { LOADCVT(nt * 4 + 1); COMPUTE(0, 0); WRITEB(TILE_B); __syncthreads(); }
            { LOADCVT(nt * 4 + 2); COMPUTE(1, TILE_B); WRITEB(0); __syncthreads(); }
            { LOADCVT(nt * 4 + 3); COMPUTE(2, 0); WRITEB(TILE_B); __syncthreads(); }
            {
                if (nt < NTILES - 1) LOADCVT(nt * 4 + 4);
                COMPUTE(3, TILE_B);
                EPI();
                if (nt < NTILES - 1) { WRITEB(0); }
                __syncthreads();
            }
        }
    }

    // ---- cross-lane sum over the 16 column lanes ----
#pragma unroll
    for (int r = 0; r < 8; ++r) {
        float S = s_run[r];
#pragma unroll
        for (int mask = 1; mask < 16; mask <<= 1) S += __shfl_xor(S, mask);
        s_run[r] = S;
    }
    if (l15 == 0) {
        const int slice = by * 2 + wc;
#pragma unroll
        for (int r = 0; r < 8; ++r) {
            const int m = r >> 2, j = r & 3;
            const int row = brow + wr * 32 + m * 16 + l4 * 4 + j;
            partials[(size_t)row * NSLICE + slice] = s_run[r];
        }
    }
}

// ---------------- kernel 4: merge slices + target logit + per-row loss ----------------
__global__ __launch_bounds__(64) void k_finalize(const float* __restrict__ partials,
                                                 const unsigned short* __restrict__ xb,
                                                 const float* __restrict__ feats,
                                                 const int* __restrict__ targets,
                                                 float* __restrict__ loss) {
    const int row  = blockIdx.x;
    const int lane = threadIdx.x;
    float S = partials[(size_t)row * NSLICE + lane];

    const int t = targets[row];
    ushort4 xv = *(const ushort4*)(xb + (size_t)row * D_DIM + lane * 4);
    float4  fv = *(const float4*)(feats + (size_t)t * D_DIM + lane * 4);
    float dot = bf2f(xv.x) * fv.x + bf2f(xv.y) * fv.y +
                bf2f(xv.z) * fv.z + bf2f(xv.w) * fv.w;   // base-2-scaled target logit
#pragma unroll
    for (int mask = 1; mask < 64; mask <<= 1) {
        S   += __shfl_xor(S, mask);
        dot += __shfl_xor(dot, mask);
    }
    if (lane == 0) loss[row] = LN2F * (__builtin_amdgcn_logf(S) - dot);
}

// ---------------- kernel 5: mean over rows ----------------
__global__ __launch_bounds__(256) void k_reduce(const float* __restrict__ loss,
                                                float* __restrict__ out) {
    __shared__ float sm[4];
    const int tid = threadIdx.x;
    float s = 0.f;
    for (int i = tid; i < B_ROWS; i += 256) s += loss[i];
#pragma unroll
    for (int mask = 1; mask < 64; mask <<= 1) s += __shfl_xor(s, mask);
    if ((tid & 63) == 0) sm[tid >> 6] = s;
    __syncthreads();
    if (tid == 0) out[0] = (sm[0] + sm[1] + sm[2] + sm[3]) * (1.0f / B_ROWS);
}

extern "C" void kernel_launch(void* const* d_in, const int* in_sizes, int n_in,
                              void* d_out, int out_size, void* d_ws, size_t ws_size,
                              hipStream_t stream) {
    const float* inputs  = (const float*)d_in[0];
    const int*   targets = (const int*)d_in[1];
    const float* feats   = (const float*)d_in[4];
    float* out = (float*)d_out;

    char* ws = (char*)d_ws;
    const size_t off_xb       = 0;                                            // 2 MB
    const size_t off_partials = off_xb + (size_t)B_ROWS * D_DIM * 2;
    const size_t off_loss     = off_partials + (size_t)B_ROWS * NSLICE * sizeof(float);
    const size_t off_fb       = off_loss + (size_t)B_ROWS * sizeof(float);
    const size_t need_fb      = off_fb + (size_t)N_FEATS * D_DIM * 2;         // +64 MB

    unsigned short* xb = (unsigned short*)(ws + off_xb);
    float* partials    = (float*)(ws + off_partials);
    float* loss        = (float*)(ws + off_loss);
    unsigned short* fb = (unsigned short*)(ws + off_fb);
    const bool precvt  = ws_size >= need_fb;

    k_normalize<<<B_ROWS, 64, 0, stream>>>(inputs, xb);
    if (precvt) {
        k_cvt_feats<<<2048, 256, 0, stream>>>(feats, fb);
        k_lse_gemm<true><<<dim3(32, NCHUNK), 512, 0, stream>>>(xb, feats, fb, partials);
    } else {
        k_lse_gemm<false><<<dim3(32, NCHUNK), 512, 0, stream>>>(xb, feats, fb, partials);
    }
    k_finalize<<<B_ROWS, 64, 0, stream>>>(partials, xb, feats, targets, loss);
    k_reduce<<<1, 256, 0, stream>>>(loss, out);
}

// Round 8
// 279.315 us; speedup vs baseline: 4.4139x; 4.4139x over previous
//
#include <hip/hip_runtime.h>
#include <hip/hip_bf16.h>

// ClusterMemory forward: loss = mean_i [ logsumexp_j( <x_i, f_j>/T ) - <x_i, f_{t_i}>/T ]
// x_i = inputs_i / max(||inputs_i||, 1e-12),  T = 0.05,  B=4096, N=131072, D=256.
//
// R8 = R4 (274us GEMM, 84 VGPR) + two safe levers:
//  (a) one barrier per TWO kt-sub-phases (32 MFMA/barrier), mid-phase counted
//      vmcnt(2) without barrier; ring-4 buffer = tile%4 stays literal.
//  (b) NCHUNK=16 -> 512 blocks = exactly 2/CU, single dispatch round.
// Max-free LSE epilogue (native v_exp_f32), A in registers for full K=256,
// B via global_load_lds(16B) inverse-swizzled, setprio around MFMA,
// bijective XCD swizzle. launch_bounds(512,2) — do NOT constrain occupancy.

typedef __attribute__((ext_vector_type(8))) short bf16x8;
typedef __attribute__((ext_vector_type(4))) float f32x4;
typedef __attribute__((address_space(1))) unsigned int u32g;
typedef __attribute__((address_space(3))) unsigned int u32l;

#define B_ROWS   4096
#define N_FEATS  131072
#define D_DIM    256
// (1/0.05) * log2(e)
#define SCALE_B2 28.853900817779268f
#define LN2F     0.69314718055994531f

#define BM 128
#define BN 128
#define BKT 64
#define NCHUNK 16                       // grid y
#define COLS_PB (N_FEATS / NCHUNK)      // 8192 cols per block
#define NTILES  (COLS_PB / BN)          // 64 column tiles per block
#define TILE_B  (BN * BKT * 2)          // 16384 bytes per B tile
#define NSLICE  (NCHUNK * 2)            // 32 partial slices per row

#define E2(x) __builtin_amdgcn_exp2f(x)

static __device__ __forceinline__ unsigned short f2bf(float x) {
    __hip_bfloat16 h = __float2bfloat16(x);
    return __builtin_bit_cast(unsigned short, h);
}
static __device__ __forceinline__ float bf2f(unsigned short u) {
    return __builtin_bit_cast(float, ((unsigned int)u) << 16);
}

// ---------------- kernel 1: row-normalize + scale + cvt to bf16 ----------------
__global__ __launch_bounds__(64) void k_normalize(const float* __restrict__ in,
                                                  unsigned short* __restrict__ xb) {
    const int row  = blockIdx.x;
    const int lane = threadIdx.x;
    float4 v = *(const float4*)(in + (size_t)row * D_DIM + lane * 4);
    float ss = v.x * v.x + v.y * v.y + v.z * v.z + v.w * v.w;
#pragma unroll
    for (int mask = 1; mask < 64; mask <<= 1) ss += __shfl_xor(ss, mask);
    const float sc = SCALE_B2 / fmaxf(sqrtf(ss), 1e-12f);
    ushort4 o;
    o.x = f2bf(v.x * sc); o.y = f2bf(v.y * sc);
    o.z = f2bf(v.z * sc); o.w = f2bf(v.w * sc);
    *(ushort4*)(xb + (size_t)row * D_DIM + lane * 4) = o;
}

// ---------------- kernel 2: features fp32 -> bf16 ----------------
__global__ __launch_bounds__(256) void k_cvt_feats(const float* __restrict__ f,
                                                   unsigned short* __restrict__ fb) {
    const int total4 = N_FEATS * D_DIM / 4;
    const int stride = gridDim.x * blockDim.x;
    for (int i = blockIdx.x * blockDim.x + threadIdx.x; i < total4; i += stride) {
        float4 v = ((const float4*)f)[i];
        ushort4 o;
        o.x = f2bf(v.x); o.y = f2bf(v.y); o.z = f2bf(v.z); o.w = f2bf(v.w);
        ((ushort4*)fb)[i] = o;
    }
}

// ---- staging: issue 2 global_load_lds (16B) for tile t_ into buffer byte-off ----
#define STAGE(t_, bOff_) do {                                                         \
        const int nt_ = (t_) >> 2, kt_ = (t_) & 3;                                    \
        const unsigned short* s_ = fb + (nbase + (size_t)nt_ * BN) * D_DIM + kt_ * BKT; \
        char* d_ = &Bs[(bOff_) + dBase];                                              \
        __builtin_amdgcn_global_load_lds((const u32g*)(s_ + e0), (u32l*)d_, 16, 0, 0);\
        __builtin_amdgcn_global_load_lds((const u32g*)(s_ + e1), (u32l*)(d_ + 8192), 16, 0, 0); \
    } while (0)

// ---- compute: 8 swizzled ds_read_b128 + 16 MFMA; ktL/bOff_ are literals ----
#define COMPUTE(ktL, bOff_) do {                                                      \
        const char* buf_ = &Bs[(bOff_)];                                              \
        bf16x8 bfr[2][4];                                                             \
        _Pragma("unroll")                                                             \
        for (int ks2 = 0; ks2 < 2; ++ks2)                                             \
        _Pragma("unroll")                                                             \
            for (int n = 0; n < 4; ++n)                                               \
                bfr[ks2][n] = *(const bf16x8*)(buf_ + dsOff[ks2][n]);                 \
        __builtin_amdgcn_s_setprio(1);                                                \
        _Pragma("unroll")                                                             \
        for (int ks2 = 0; ks2 < 2; ++ks2)                                             \
        _Pragma("unroll")                                                             \
            for (int m = 0; m < 2; ++m)                                               \
        _Pragma("unroll")                                                             \
                for (int n = 0; n < 4; ++n)                                           \
                    acc[m][n] = __builtin_amdgcn_mfma_f32_16x16x32_bf16(              \
                        afr[m][(ktL) * 2 + ks2], bfr[ks2][n], acc[m][n], 0, 0, 0);    \
        __builtin_amdgcn_s_setprio(0);                                                \
    } while (0)

// waitcnt-only and waitcnt+barrier
#define WC(n_)  asm volatile("s_waitcnt vmcnt(" #n_ ")" ::: "memory")
#define VMB(n_) asm volatile("s_waitcnt vmcnt(" #n_ ")\ns_barrier" ::: "memory")

// ---- per-column-tile exp2-accumulate (max-free; logits bounded); resets acc ----
#define EPI() do {                                                                    \
        _Pragma("unroll")                                                             \
        for (int m = 0; m < 2; ++m)                                                   \
        _Pragma("unroll")                                                             \
            for (int j = 0; j < 4; ++j) {                                             \
                const int r = m * 4 + j;                                              \
                s_run[r] += (E2(acc[m][0][j]) + E2(acc[m][1][j]))                     \
                          + (E2(acc[m][2][j]) + E2(acc[m][3][j]));                    \
            }                                                                         \
        _Pragma("unroll")                                                             \
        for (int m = 0; m < 2; ++m)                                                   \
        _Pragma("unroll")                                                             \
            for (int n = 0; n < 4; ++n) acc[m][n] = (f32x4){0.f, 0.f, 0.f, 0.f};      \
    } while (0)

// ---- fp32-fallback staging (reg-cvt, write-side swizzle) ----
#define LOADCVT(t_) do {                                                              \
        const int nt_ = (t_) >> 2, kt_ = (t_) & 3;                                    \
        const float* s0_ = featf + (nbase + (size_t)nt_ * BN + fc0) * D_DIM + kt_ * BKT + fk0; \
        const float* s1_ = featf + (nbase + (size_t)nt_ * BN + fc1) * D_DIM + kt_ * BKT + fk1; \
        float4 a0 = *(const float4*)s0_, a1 = *(const float4*)(s0_ + 4);              \
        float4 b0 = *(const float4*)s1_, b1 = *(const float4*)(s1_ + 4);              \
        unsigned short ua[8] = {f2bf(a0.x), f2bf(a0.y), f2bf(a0.z), f2bf(a0.w),       \
                                f2bf(a1.x), f2bf(a1.y), f2bf(a1.z), f2bf(a1.w)};      \
        unsigned short ub[8] = {f2bf(b0.x), f2bf(b0.y), f2bf(b0.z), f2bf(b0.w),       \
                                f2bf(b1.x), f2bf(b1.y), f2bf(b1.z), f2bf(b1.w)};      \
        ra = *(int4*)ua; rb = *(int4*)ub;                                             \
    } while (0)
#define WRITEB(bOff_) do {                                                            \
        char* d_ = &Bs[(bOff_)];                                                      \
        *(int4*)(d_ + wo0) = ra;                                                      \
        *(int4*)(d_ + wo1) = rb;                                                      \
    } while (0)

// ---------------- kernel 3: fused GEMM + max-free base-2 LSE ----------------
// grid = (32 m-blocks, 16 n-chunks) = 512 blocks (2/CU), block = 512 (8 waves: 4wr x 2wc)
template <bool BF16B>
__global__ __launch_bounds__(512, 2) void k_lse_gemm(
    const unsigned short* __restrict__ xb,
    const float* __restrict__ featf,
    const unsigned short* __restrict__ fb,
    float* __restrict__ partials)
{
    __shared__ char Bs[4 * TILE_B];   // 64 KB ring

    // bijective XCD swizzle (512 blocks % 8 == 0)
    const int hw  = blockIdx.y * 32 + blockIdx.x;
    const int lid = (hw & 7) * 64 + (hw >> 3);
    const int bx  = lid & 31;         // m-block  0..31
    const int by  = lid >> 5;         // n-chunk  0..15

    const int tid  = threadIdx.x;
    const int lane = tid & 63;
    const int w    = tid >> 6;
    const int wr   = w >> 1;          // 0..3 : 32-row slice
    const int wc   = w & 1;           // 0..1 : 64-col slice
    const int l15  = lane & 15;
    const int l4   = lane >> 4;

    const int brow     = bx * BM;
    const size_t nbase = (size_t)by * COLS_PB;

    // hoisted swizzled ds_read byte offsets (loop-invariant)
    int dsOff[2][4];
#pragma unroll
    for (int ks2 = 0; ks2 < 2; ++ks2)
#pragma unroll
        for (int n = 0; n < 4; ++n) {
            const int col = wc * 64 + n * 16 + l15;
            dsOff[ks2][n] = (col * 128 + ks2 * 64 + l4 * 16) ^ ((col & 7) << 4);
        }

    // ---- A fragments in registers for full K=256 (loaded once, L2-resident) ----
    bf16x8 afr[2][8];
#pragma unroll
    for (int m = 0; m < 2; ++m) {
        const unsigned short* ap =
            xb + (size_t)(brow + wr * 32 + m * 16 + l15) * D_DIM + l4 * 8;
#pragma unroll
        for (int ks = 0; ks < 8; ++ks)
            afr[m][ks] = *(const bf16x8*)(ap + ks * 32);
    }

    f32x4 acc[2][4];
#pragma unroll
    for (int m = 0; m < 2; ++m)
#pragma unroll
        for (int n = 0; n < 4; ++n) acc[m][n] = (f32x4){0.f, 0.f, 0.f, 0.f};
    float s_run[8];
#pragma unroll
    for (int r = 0; r < 8; ++r) s_run[r] = 0.f;

    if (BF16B) {
        // inverse-swizzled source element offsets (constant across tiles)
        int e0, e1;
        {
            const int p0 = w * 1024 + lane * 16;
            const int c0 = p0 >> 7;
            e0 = c0 * D_DIM + ((((p0 ^ ((c0 & 7) << 4)) >> 4) & 7) * 8);
            const int p1 = p0 + 8192;
            const int c1 = p1 >> 7;
            e1 = c1 * D_DIM + ((((p1 ^ ((c1 & 7) << 4)) >> 4) & 7) * 8);
        }
        const int dBase = w * 1024;   // wave-uniform LDS slice

        // buffer for tile t is (t%4)*TILE_B — literal per kt position.
        STAGE(0, 0);
        STAGE(1, TILE_B);
        for (int nt = 0; nt < NTILES - 1; ++nt) {
            const int t0 = nt * 4;
            // super-phase A: kt 0,1  (one barrier)
            VMB(2);                               // tile t0 done; prev readers done
            STAGE(t0 + 2, 2 * TILE_B);            // b2: readers finished before barrier
            COMPUTE(0, 0);                        // read tile t0 (b0)
            WC(2);                                // tile t0+1 done
            STAGE(t0 + 3, 3 * TILE_B);            // b3
            COMPUTE(1, TILE_B);                   // read tile t0+1 (b1)
            // super-phase B: kt 2,3  (one barrier)
            VMB(2);                               // tile t0+2 done; b0/b1 readers done
            STAGE(t0 + 4, 0);                     // b0
            COMPUTE(2, 2 * TILE_B);               // read tile t0+2 (b2)
            WC(2);                                // tile t0+3 done
            STAGE(t0 + 5, TILE_B);                // b1
            COMPUTE(3, 3 * TILE_B);               // read tile t0+3 (b3)
            EPI();
        }
        // peeled nt = NTILES-1: tiles 4nt..4nt+3; A stages last two tiles, B stages none
        {
            const int t0 = (NTILES - 1) * 4;
            VMB(2);
            STAGE(t0 + 2, 2 * TILE_B);
            COMPUTE(0, 0);
            WC(2);
            STAGE(t0 + 3, 3 * TILE_B);
            COMPUTE(1, TILE_B);
            VMB(2);
            COMPUTE(2, 2 * TILE_B);
            WC(0);
            COMPUTE(3, 3 * TILE_B);
            EPI();
        }
    } else {
        // fp32 fallback: reg-staged cvt, 2-buffer, __syncthreads discipline
        const int c0 = tid, c1 = tid + 512;
        const int fc0 = c0 >> 3, fk0 = (c0 & 7) * 8;
        const int fc1 = c1 >> 3, fk1 = (c1 & 7) * 8;
        const int wo0 = (fc0 * 128 + fk0 * 2) ^ ((fc0 & 7) << 4);
        const int wo1 = (fc1 * 128 + fk1 * 2) ^ ((fc1 & 7) << 4);
        int4 ra, rb;
        LOADCVT(0); WRITEB(0);
        __syncthreads();
        for (int nt = 0; nt < NTILES; ++nt) {
            { LOADCVT(nt * 4 + 1); COMPUTE(0, 0); WRITEB(TILE_B); __syncthreads(); }
            { LOADCVT(nt * 4 + 2); COMPUTE(1, TILE_B); WRITEB(0); __syncthreads(); }
            { LOADCVT(nt * 4 + 3); COMPUTE(2, 0); WRITEB(TILE_B); __syncthreads(); }
            {
                if (nt < NTILES - 1) LOADCVT(nt * 4 + 4);
                COMPUTE(3, TILE_B);
                EPI();
                if (nt < NTILES - 1) { WRITEB(0); }
                __syncthreads();
            }
        }
    }

    // ---- cross-lane sum over the 16 column lanes ----
#pragma unroll
    for (int r = 0; r < 8; ++r) {
        float S = s_run[r];
#pragma unroll
        for (int mask = 1; mask < 16; mask <<= 1) S += __shfl_xor(S, mask);
        s_run[r] = S;
    }
    if (l15 == 0) {
        const int slice = by * 2 + wc;
#pragma unroll
        for (int r = 0; r < 8; ++r) {
            const int m = r >> 2, j = r & 3;
            const int row = brow + wr * 32 + m * 16 + l4 * 4 + j;
            partials[(size_t)row * NSLICE + slice] = s_run[r];
        }
    }
}

// ---------------- kernel 4: merge slices + target logit + per-row loss ----------------
__global__ __launch_bounds__(64) void k_finalize(const float* __restrict__ partials,
                                                 const unsigned short* __restrict__ xb,
                                                 const float* __restrict__ feats,
                                                 const int* __restrict__ targets,
                                                 float* __restrict__ loss) {
    const int row  = blockIdx.x;
    const int lane = threadIdx.x;
    float S = (lane < NSLICE) ? partials[(size_t)row * NSLICE + lane] : 0.0f;

    const int t = targets[row];
    ushort4 xv = *(const ushort4*)(xb + (size_t)row * D_DIM + lane * 4);
    float4  fv = *(const float4*)(feats + (size_t)t * D_DIM + lane * 4);
    float dot = bf2f(xv.x) * fv.x + bf2f(xv.y) * fv.y +
                bf2f(xv.z) * fv.z + bf2f(xv.w) * fv.w;   // base-2-scaled target logit
#pragma unroll
    for (int mask = 1; mask < 64; mask <<= 1) {
        S   += __shfl_xor(S, mask);
        dot += __shfl_xor(dot, mask);
    }
    if (lane == 0) loss[row] = LN2F * (__builtin_amdgcn_logf(S) - dot);
}

// ---------------- kernel 5: mean over rows ----------------
__global__ __launch_bounds__(256) void k_reduce(const float* __restrict__ loss,
                                                float* __restrict__ out) {
    __shared__ float sm[4];
    const int tid = threadIdx.x;
    float s = 0.f;
    for (int i = tid; i < B_ROWS; i += 256) s += loss[i];
#pragma unroll
    for (int mask = 1; mask < 64; mask <<= 1) s += __shfl_xor(s, mask);
    if ((tid & 63) == 0) sm[tid >> 6] = s;
    __syncthreads();
    if (tid == 0) out[0] = (sm[0] + sm[1] + sm[2] + sm[3]) * (1.0f / B_ROWS);
}

extern "C" void kernel_launch(void* const* d_in, const int* in_sizes, int n_in,
                              void* d_out, int out_size, void* d_ws, size_t ws_size,
                              hipStream_t stream) {
    const float* inputs  = (const float*)d_in[0];
    const int*   targets = (const int*)d_in[1];
    const float* feats   = (const float*)d_in[4];
    float* out = (float*)d_out;

    char* ws = (char*)d_ws;
    const size_t off_xb       = 0;                                            // 2 MB
    const size_t off_partials = off_xb + (size_t)B_ROWS * D_DIM * 2;
    const size_t off_loss     = off_partials + (size_t)B_ROWS * NSLICE * sizeof(float);
    const size_t off_fb       = off_loss + (size_t)B_ROWS * sizeof(float);
    const size_t need_fb      = off_fb + (size_t)N_FEATS * D_DIM * 2;         // +64 MB

    unsigned short* xb = (unsigned short*)(ws + off_xb);
    float* partials    = (float*)(ws + off_partials);
    float* loss        = (float*)(ws + off_loss);
    unsigned short* fb = (unsigned short*)(ws + off_fb);
    const bool precvt  = ws_size >= need_fb;

    k_normalize<<<B_ROWS, 64, 0, stream>>>(inputs, xb);
    if (precvt) {
        k_cvt_feats<<<2048, 256, 0, stream>>>(feats, fb);
        k_lse_gemm<true><<<dim3(32, NCHUNK), 512, 0, stream>>>(xb, feats, fb, partials);
    } else {
        k_lse_gemm<false><<<dim3(32, NCHUNK), 512, 0, stream>>>(xb, feats, fb, partials);
    }
    k_finalize<<<B_ROWS, 64, 0, stream>>>(partials, xb, feats, targets, loss);
    k_reduce<<<1, 256, 0, stream>>>(loss, out);
}